// Round 4
// baseline (105.149 us; speedup 1.0000x reference)
//
#include <hip/hip_runtime.h>
#include <hip/hip_bf16.h>

typedef __bf16 bf16x8 __attribute__((ext_vector_type(8)));
typedef __bf16 bf16x4 __attribute__((ext_vector_type(4)));
typedef float  f32x4  __attribute__((ext_vector_type(4)));

#define SEQ 4096
#define CIN 64
#define KBLK 128
#define NT (SEQ / KBLK)
#define LOG2E 1.44269504088896340736f

__device__ __forceinline__ void gll16(const void* g, void* l) {
    __builtin_amdgcn_global_load_lds(
        (const __attribute__((address_space(1))) void*)g,
        (__attribute__((address_space(3))) void*)l, 16, 0, 0);
}

// ---------------------------------------------------------------------------
// Kernel 1: fused conv1x1 + PReLU producing Q,K (as [n][4096][32] bf16) and
// Vt (as [n][64][4096] bf16). Q pre-scaled by log2(e) so attn uses exp2.
// ---------------------------------------------------------------------------
__global__ __launch_bounds__(256, 2) void qkv_gen(
    const float* __restrict__ x,
    const float* __restrict__ w1, const float* __restrict__ b1, const float* __restrict__ a1,
    const float* __restrict__ w2, const float* __restrict__ b2, const float* __restrict__ a2,
    const float* __restrict__ w3, const float* __restrict__ b3, const float* __restrict__ a3,
    __bf16* __restrict__ qws, __bf16* __restrict__ kws, __bf16* __restrict__ vtws)
{
    __shared__ float xs[CIN][64];
    __shared__ float wl[CIN][128];
    __shared__ float bl[128];
    __shared__ float al[4];

    const int t  = threadIdx.x;
    const int n  = blockIdx.x >> 6;
    const int p0 = (blockIdx.x & 63) << 6;

    for (int idx = t; idx < 2048; idx += 256) {
        int j = idx >> 6, c = idx & 63;
        wl[c][j]      = w1[idx];
        wl[c][32 + j] = w2[idx];
    }
    for (int idx = t; idx < 4096; idx += 256) {
        int j = idx >> 6, c = idx & 63;
        wl[c][64 + j] = w3[idx];
    }
    if (t < 32) { bl[t] = b1[t]; bl[32 + t] = b2[t]; }
    if (t >= 128 && t < 192) bl[64 + (t - 128)] = b3[t - 128];
    if (t == 0) { al[0] = a1[0]; al[1] = a2[0]; al[2] = a3[0]; }

    const float* xb = x + ((size_t)n * CIN) * SEQ + p0;
    for (int r = 0; r < 16; ++r) {
        int e = r * 256 + t;
        xs[e >> 6][e & 63] = xb[(size_t)(e >> 6) * SEQ + (e & 63)];
    }
    __syncthreads();

    const int p  = t & 63;
    const int g  = t >> 6;
    const int jb = g << 5;
    const float a = (g == 0) ? al[0] : ((g == 1) ? al[1] : al[2]);

    float acc[32];
    #pragma unroll
    for (int j = 0; j < 32; ++j) acc[j] = bl[jb + j];

    for (int c = 0; c < CIN; ++c) {
        float xv = xs[c][p];
        const f32x4* wr = (const f32x4*)&wl[c][jb];
        #pragma unroll
        for (int j4 = 0; j4 < 8; ++j4) {
            f32x4 wv = wr[j4];
            acc[j4*4+0] = fmaf(wv[0], xv, acc[j4*4+0]);
            acc[j4*4+1] = fmaf(wv[1], xv, acc[j4*4+1]);
            acc[j4*4+2] = fmaf(wv[2], xv, acc[j4*4+2]);
            acc[j4*4+3] = fmaf(wv[3], xv, acc[j4*4+3]);
        }
    }
    #pragma unroll
    for (int j = 0; j < 32; ++j) acc[j] = acc[j] >= 0.f ? acc[j] : a * acc[j];

    const int pg = p0 + p;
    if (g <= 1) {
        const float sc = (g == 0) ? LOG2E : 1.0f;
        __bf16* dst = (g == 0 ? qws : kws) + ((size_t)n * SEQ + pg) * 32;
        #pragma unroll
        for (int v8 = 0; v8 < 4; ++v8) {
            bf16x8 o;
            #pragma unroll
            for (int i = 0; i < 8; ++i) o[i] = (__bf16)(acc[v8*8+i] * sc);
            *(bf16x8*)(dst + v8*8) = o;
        }
    } else {
        __bf16* dst = vtws + ((size_t)n * CIN + (jb - 64)) * SEQ + pg;
        #pragma unroll
        for (int j = 0; j < 32; ++j) dst[(size_t)j * SEQ] = (__bf16)acc[j];
    }
}

// ---------------------------------------------------------------------------
// Kernel 2: flash attention, fixed-max softmax. 512 blocks (n=bid&7 XCD-affine,
// qblk=bid>>3), 2 waves x 32 q-rows (2 q-tiles/wave). KBLK=128, double-buffered
// K/V via global_load_lds (pre-swizzled sources). K-frag and V-frag LDS reads
// are shared across both q-tiles -> 1.6x less LDS traffic per q.
// K tile swizzle: byte ^= ((row>>1)&3)<<4  (row=key, 64B rows)
// V/P tile swizzle: byte ^= (row&7)<<4     (256B rows)
// ---------------------------------------------------------------------------
__global__ __launch_bounds__(128) void attn(
    const __bf16* __restrict__ qws, const __bf16* __restrict__ kws,
    const __bf16* __restrict__ vtws, const float* __restrict__ x,
    float* __restrict__ out)
{
    __shared__ __align__(16) char kt[2][KBLK * 64];    // 2 x 8 KB
    __shared__ __align__(16) char vt[2][CIN * 256];    // 2 x 16 KB
    __shared__ __align__(16) char pt[2][32 * 256];     // 2 x 8 KB (per-wave P, 32qx128k)

    const int t    = threadIdx.x;    // 128 threads, 2 waves
    const int lane = t & 63;
    const int wid  = t >> 6;
    const int n    = blockIdx.x & 7;
    const int qblk = blockIdx.x >> 3;
    const int r16  = lane & 15;
    const int g4   = lane >> 4;
    const int qbase = qblk * 64 + wid * 32;
    const int sw   = (r16 & 7) << 4;            // V/P swizzle
    const int ksw  = ((r16 >> 1) & 3) << 4;     // K read swizzle (lane-invariant in f)

    const char* kb = (const char*)(kws + (size_t)n * SEQ * 32);
    const char* vb = (const char*)(vtws + (size_t)n * CIN * SEQ);
    char* pw = &pt[wid][0];

    const char* qbase_p = (const char*)(qws + (size_t)n * SEQ * 32);
    const bf16x8 qf0 = *(const bf16x8*)(qbase_p + (size_t)(qbase + r16) * 64 + g4 * 16);
    const bf16x8 qf1 = *(const bf16x8*)(qbase_p + (size_t)(qbase + 16 + r16) * 64 + g4 * 16);

    f32x4 of0[4] = {}, of1[4] = {};
    f32x4 ls0 = {0.f,0.f,0.f,0.f}, ls1 = {0.f,0.f,0.f,0.f};

    // ---- stage tile k0n into buf (128 threads). Sources pre-swizzled. ----
    auto stage = [&](int k0n, int buf) {
        // K: 8 KB, rows=key (64 B). dest linear L; src col16 ^= (row>>1)&3
        #pragma unroll
        for (int j = 0; j < 4; ++j) {
            int L   = j * 2048 + t * 16;
            int row = L >> 6;                       // j*32 + (t>>2)
            int c16 = (t & 3) ^ ((t >> 3) & 3);     // (L>>4&3) ^ ((row>>1)&3)
            gll16(kb + (size_t)(k0n + row) * 64 + c16 * 16, &kt[buf][0] + L);
        }
        // V: 16 KB, rows=dv (256 B). src colb ^= (row&7)<<4
        #pragma unroll
        for (int j = 0; j < 8; ++j) {
            int L    = j * 2048 + t * 16;
            int row  = L >> 8;                      // j*8 + (t>>4)
            int colb = (t & 15) * 16;
            gll16(vb + (size_t)row * 8192 + k0n * 2 + (colb ^ ((row & 7) << 4)),
                  &vt[buf][0] + L);
        }
    };

    stage(0, 0);
    __syncthreads();

    for (int tt = 0; tt < NT; ++tt) {
        const int cur = tt & 1;
        if (tt + 1 < NT) stage((tt + 1) * KBLK, cur ^ 1);

        const char* kc_ = &kt[cur][0];
        const char* vc_ = &vt[cur][0];

        // ---- S^T for both q-tiles: K frag loaded once, 2 MFMAs each ----
        f32x4 st0[8], st1[8];
        __builtin_amdgcn_s_setprio(1);
        #pragma unroll
        for (int f = 0; f < 8; ++f) {
            bf16x8 kf = *(const bf16x8*)(kc_ + (f * 16 + r16) * 64 + (g4 * 16 ^ ksw));
            f32x4 z = {0.f, 0.f, 0.f, 0.f};
            st0[f] = __builtin_amdgcn_mfma_f32_16x16x32_bf16(kf, qf0, z, 0, 0, 0);
            st1[f] = __builtin_amdgcn_mfma_f32_16x16x32_bf16(kf, qf1, z, 0, 0, 0);
        }
        __builtin_amdgcn_s_setprio(0);

        // ---- softmax qt0: exp2, rowsum, pack -> P rows [0,16) ----
        #pragma unroll
        for (int f = 0; f < 8; ++f) {
            f32x4 e;
            e[0] = __builtin_exp2f(st0[f][0]);
            e[1] = __builtin_exp2f(st0[f][1]);
            e[2] = __builtin_exp2f(st0[f][2]);
            e[3] = __builtin_exp2f(st0[f][3]);
            ls0 += e;
            bf16x4 pk;
            pk[0] = (__bf16)e[0]; pk[1] = (__bf16)e[1];
            pk[2] = (__bf16)e[2]; pk[3] = (__bf16)e[3];
            *(bf16x4*)(pw + r16 * 256 + ((f * 32 + g4 * 8) ^ sw)) = pk;
        }
        // ---- softmax qt1 -> P rows [16,32) (overlaps PV qt0 scheduling) ----
        #pragma unroll
        for (int f = 0; f < 8; ++f) {
            f32x4 e;
            e[0] = __builtin_exp2f(st1[f][0]);
            e[1] = __builtin_exp2f(st1[f][1]);
            e[2] = __builtin_exp2f(st1[f][2]);
            e[3] = __builtin_exp2f(st1[f][3]);
            ls1 += e;
            bf16x4 pk;
            pk[0] = (__bf16)e[0]; pk[1] = (__bf16)e[1];
            pk[2] = (__bf16)e[2]; pk[3] = (__bf16)e[3];
            *(bf16x4*)(pw + (16 + r16) * 256 + ((f * 32 + g4 * 8) ^ sw)) = pk;
        }

        // ---- O^T += Vt . P^T : V frag loaded once, used by both q-tiles ----
        __builtin_amdgcn_s_setprio(1);
        #pragma unroll
        for (int kc2 = 0; kc2 < 4; ++kc2) {
            const int col = (kc2 * 64 + g4 * 16) ^ sw;
            bf16x8 pf0 = *(const bf16x8*)(pw + r16 * 256 + col);
            bf16x8 pf1 = *(const bf16x8*)(pw + (16 + r16) * 256 + col);
            #pragma unroll
            for (int fd = 0; fd < 4; ++fd) {
                bf16x8 vf = *(const bf16x8*)(vc_ + (fd * 16 + r16) * 256 + col);
                of0[fd] = __builtin_amdgcn_mfma_f32_16x16x32_bf16(vf, pf0, of0[fd], 0, 0, 0);
                of1[fd] = __builtin_amdgcn_mfma_f32_16x16x32_bf16(vf, pf1, of1[fd], 0, 0, 0);
            }
        }
        __builtin_amdgcn_s_setprio(0);

        __syncthreads();   // waves drain vm/lgkm; protects dbuf swap
    }

    // ---- epilogue ----
    float l0 = ls0[0] + ls0[1] + ls0[2] + ls0[3];
    float l1 = ls1[0] + ls1[1] + ls1[2] + ls1[3];
    l0 += __shfl_xor(l0, 16); l0 += __shfl_xor(l0, 32);
    l1 += __shfl_xor(l1, 16); l1 += __shfl_xor(l1, 32);
    const float inv0 = 1.f / l0, inv1 = 1.f / l1;
    const float* xb = x + (size_t)n * CIN * SEQ;
    float* ob = out + (size_t)n * CIN * SEQ;
    #pragma unroll
    for (int fd = 0; fd < 4; ++fd)
        #pragma unroll
        for (int r = 0; r < 4; ++r) {
            size_t rowoff = (size_t)(fd * 16 + g4 * 4 + r) * SEQ + qbase + r16;
            ob[rowoff]      = of0[fd][r] * inv0 + xb[rowoff];
            ob[rowoff + 16] = of1[fd][r] * inv1 + xb[rowoff + 16];
        }
}

extern "C" void kernel_launch(void* const* d_in, const int* in_sizes, int n_in,
                              void* d_out, int out_size, void* d_ws, size_t ws_size,
                              hipStream_t stream)
{
    (void)in_sizes; (void)n_in; (void)out_size; (void)ws_size;
    const float* x  = (const float*)d_in[0];
    const float* w1 = (const float*)d_in[1];
    const float* b1 = (const float*)d_in[2];
    const float* a1 = (const float*)d_in[3];
    const float* w2 = (const float*)d_in[4];
    const float* b2 = (const float*)d_in[5];
    const float* a2 = (const float*)d_in[6];
    const float* w3 = (const float*)d_in[7];
    const float* b3 = (const float*)d_in[8];
    const float* a3 = (const float*)d_in[9];
    float* out = (float*)d_out;

    __bf16* qws  = (__bf16*)d_ws;                       // 2 MB
    __bf16* kws  = qws + (size_t)8 * SEQ * 32;          // 2 MB
    __bf16* vtws = kws + (size_t)8 * SEQ * 32;          // 4 MB

    hipLaunchKernelGGL(qkv_gen, dim3(512), dim3(256), 0, stream,
                       x, w1, b1, a1, w2, b2, a2, w3, b3, a3, qws, kws, vtws);
    hipLaunchKernelGGL(attn, dim3(512), dim3(128), 0, stream,
                       qws, kws, vtws, x, out);
}